// Round 1
// 151.070 us; speedup vs baseline: 1.1305x; 1.1305x over previous
//
#include <hip/hip_runtime.h>
#include <math.h>

#define BB 8
#define CC 512
#define LL 1024
#define GG 32
#define CPG 16
#define NH 8
#define CH 64

typedef unsigned short ushort_t;
typedef __attribute__((ext_vector_type(8))) short short8;
typedef __attribute__((ext_vector_type(4))) float f32x4;

#define SCALE_Q 0.18033688f  // 0.125 * log2(e)

__device__ inline ushort_t f2bf(float f) {
  union { float f; unsigned u; } v;
  v.f = f;
  unsigned r = v.u + 0x7FFFu + ((v.u >> 16) & 1u);
  return (ushort_t)(r >> 16);
}

// pack two f32 -> two bf16 (truncate) in one v_perm_b32
__device__ inline unsigned pack_bf2(float lo, float hi) {
  return __builtin_amdgcn_perm(__float_as_uint(hi), __float_as_uint(lo),
                               0x07060302u);
}

// XOR-swizzled LDS index: rows of 64 bf16, 8-elt groups swizzled by row&7.
// Involution: applied once at the producer (global image) and once at the
// ds_read -> conflict-free fragment reads with LINEAR global_load_lds staging.
__device__ inline int swz(int r, int k) {
  return r * 64 + ((((k >> 3) ^ (r & 7)) << 3) | (k & 7));
}

// async 16B global->LDS (DMA). LDS dest = wave-uniform base + lane*16.
__device__ __forceinline__ void g2l16(const void* g, void* l) {
  __builtin_amdgcn_global_load_lds((const unsigned int*)g, (unsigned int*)l,
                                   16, 0, 0);
}

// ---------------- GroupNorm stats + weight convert (merged) ----------------
// blocks [0,256): GN stats (float4 loads); blocks [256,1280): fp32->bf16
// weight convert writing PRE-SWIZZLED images of wq/wp.
__global__ __launch_bounds__(256) void pre_kernel(
    const float* __restrict__ x, const float* __restrict__ gn_w,
    const float* __restrict__ gn_b, const float* __restrict__ qkv_w,
    const float* __restrict__ proj_w, float* __restrict__ s_bc,
    float* __restrict__ t_bc, ushort_t* __restrict__ wq,
    ushort_t* __restrict__ wp) {
  if (blockIdx.x < BB * GG) {
    int b = blockIdx.x / GG;
    int g = blockIdx.x % GG;
    const float4* xg4 =
        (const float4*)(x + ((size_t)b * CC + (size_t)g * CPG) * LL);
    float sum = 0.f, sq = 0.f;
#pragma unroll
    for (int i = 0; i < 16; ++i) {
      float4 v = xg4[threadIdx.x + i * 256];
      sum += (v.x + v.y) + (v.z + v.w);
      sq += (v.x * v.x + v.y * v.y) + (v.z * v.z + v.w * v.w);
    }
#pragma unroll
    for (int off = 32; off > 0; off >>= 1) {
      sum += __shfl_down(sum, off);
      sq += __shfl_down(sq, off);
    }
    __shared__ float red[8];
    __shared__ float st[2];
    int wave = threadIdx.x >> 6;
    if ((threadIdx.x & 63) == 0) {
      red[wave] = sum;
      red[4 + wave] = sq;
    }
    __syncthreads();
    if (threadIdx.x == 0) {
      float s = red[0] + red[1] + red[2] + red[3];
      float q = red[4] + red[5] + red[6] + red[7];
      float mean = s * (1.f / (CPG * LL));
      float var = q * (1.f / (CPG * LL)) - mean * mean;
      st[0] = mean;
      st[1] = rsqrtf(var + 1e-5f);
    }
    __syncthreads();
    if (threadIdx.x < CPG) {
      int c = g * CPG + threadIdx.x;
      float w = gn_w[c];
      float sc = st[1] * w;
      s_bc[b * CC + c] = sc;
      t_bc[b * CC + c] = gn_b[c] - st[0] * sc;
    }
  } else {
    int cb = blockIdx.x - BB * GG;
    int idx = (cb * 256 + threadIdx.x) * 4;
    const int N1 = 3 * CC * CC;
    float4 v;
    ushort_t* mat;
    int row, k;
    if (idx < N1) {
      v = *(const float4*)(qkv_w + idx);
      row = idx >> 9;
      k = idx & 511;
      mat = wq + (size_t)row * CC;
    } else {
      int j = idx - N1;
      v = *(const float4*)(proj_w + j);
      row = j >> 9;
      k = j & 511;
      mat = wp + (size_t)row * CC;
    }
    // pre-swizzle: 8-elt group ^= row&7 within each 64-col block
    int dcol = (k & ~63) | ((((k >> 3) & 7) ^ (row & 7)) << 3) | (k & 7);
    unsigned lo = f2bf(v.x) | ((unsigned)f2bf(v.y) << 16);
    unsigned hi = f2bf(v.z) | ((unsigned)f2bf(v.w) << 16);
    *(uint2*)(mat + dcol) = make_uint2(lo, hi);
  }
}

// ---------------- GN apply + transpose -> xnT[b][l][c] bf16 (pre-swizzled) --
__global__ __launch_bounds__(256) void xnt_kernel(
    const float* __restrict__ x, const float* __restrict__ s_bc,
    const float* __restrict__ t_bc, ushort_t* __restrict__ xnT) {
  const int b = blockIdx.z;
  const int c0 = blockIdx.y * 64;
  const int l0 = blockIdx.x * 64;
  const int tid = threadIdx.x;
  __shared__ ushort_t Ts[64 * 72];
#pragma unroll
  for (int r4 = 0; r4 < 4; ++r4) {
    int c_local = (tid >> 4) + r4 * 16;
    int l_local = (tid & 15) * 4;
    int c = c0 + c_local;
    float sc = s_bc[b * CC + c], sh = t_bc[b * CC + c];
    float4 v = *(const float4*)(x + ((size_t)b * CC + c) * LL + l0 + l_local);
    float vv[4] = {v.x, v.y, v.z, v.w};
#pragma unroll
    for (int dl = 0; dl < 4; ++dl) {
      int l = l_local + dl;
      int cs = c_local ^ (((l >> 2) & 7) << 3);
      Ts[l * 72 + cs] = f2bf(vv[dl] * sc + sh);
    }
  }
  __syncthreads();
#pragma unroll
  for (int rep = 0; rep < 2; ++rep) {
    int gid = tid + rep * 256;
    int l = gid >> 3, seg = gid & 7;
    uint4 v = *(const uint4*)&Ts[l * 72 + ((seg * 8) ^ (((l >> 2) & 7) << 3))];
    // pre-swizzled global image: group seg -> seg ^ (l&7)
    *(uint4*)(xnT + ((size_t)b * LL + l0 + l) * CC + c0 +
              ((seg ^ (l & 7)) << 3)) = v;
  }
}

// ---------------- QKV GEMM: m97-structure (global_load_lds staging) --------
__global__ __launch_bounds__(256) void qkv_mfma_kernel(
    const ushort_t* __restrict__ wq, const ushort_t* __restrict__ xnT,
    const float* __restrict__ qkv_b, ushort_t* __restrict__ qT,
    ushort_t* __restrict__ kT, ushort_t* __restrict__ vbuf) {
  const int b = blockIdx.z;
  const int m0 = blockIdx.y * 128;
  const int n0 = blockIdx.x * 128;
  const int tid = threadIdx.x;
  const int w = tid >> 6, lane = tid & 63;
  const int col = lane & 15, quad = lane >> 4;
  const int wm = (w >> 1) * 64, wn = (w & 1) * 64;
  __shared__ ushort_t Smem[2 * 128 * 64];  // 32KB: As | Bs, reused by epilogue
  ushort_t* As = Smem;
  ushort_t* Bs = Smem + 128 * 64;
  f32x4 acc[4][4];
  f32x4 z = {0.f, 0.f, 0.f, 0.f};
#pragma unroll
  for (int i = 0; i < 4; ++i)
#pragma unroll
    for (int j = 0; j < 4; ++j) acc[i][j] = z;

  const ushort_t* arow = wq + (size_t)m0 * CC;
  const ushort_t* brow = xnT + ((size_t)b * LL + n0) * CC;
  const int eb = w * 2048 + lane * 8;  // flat ushort idx of lane's 16B

  for (int k0 = 0; k0 < CC; k0 += 64) {
    __syncthreads();  // all waves done with previous tile's fragments
#pragma unroll
    for (int i = 0; i < 4; ++i) {
      int ee = eb + i * 512;
      int r = ee >> 6, c = ee & 63;
      g2l16(arow + (size_t)r * CC + k0 + c, As + (w * 2048 + i * 512));
      g2l16(brow + (size_t)r * CC + k0 + c, Bs + (w * 2048 + i * 512));
    }
    __syncthreads();  // implicit vmcnt(0): staged tiles visible
#pragma unroll
    for (int kk = 0; kk < 2; ++kk) {
      short8 af[4], bf[4];
#pragma unroll
      for (int mi = 0; mi < 4; ++mi)
        af[mi] = *(const short8*)&As[swz(wm + mi * 16 + col, kk * 32 + quad * 8)];
#pragma unroll
      for (int ni = 0; ni < 4; ++ni)
        bf[ni] = *(const short8*)&Bs[swz(wn + ni * 16 + col, kk * 32 + quad * 8)];
#pragma unroll
      for (int mi = 0; mi < 4; ++mi)
#pragma unroll
        for (int ni = 0; ni < 4; ++ni)
          acc[mi][ni] = __builtin_amdgcn_mfma_f32_16x16x32_bf16(
              af[mi], bf[ni], acc[mi][ni], 0, 0, 0);
    }
  }
  // ---- epilogue: transpose through LDS, coalesced b128 stores ----
  __syncthreads();  // all waves done reading As/Bs
  const int chunk_g = (m0 >> 6) + (w >> 1);
  const int sel = chunk_g % 3;
  ushort_t* Tile = Smem + (w >> 1) * 8192;
  if (sel < 2) {
    // q/k: Tile as [l 128][ch 64], xor-swizzled == pre-swizzled global image
    const float sc = (sel == 0) ? SCALE_Q : 1.f;
#pragma unroll
    for (int mi = 0; mi < 4; ++mi) {
      int mg = m0 + wm + mi * 16 + quad * 4;
      float b0 = qkv_b[mg + 0], b1 = qkv_b[mg + 1];
      float b2 = qkv_b[mg + 2], b3 = qkv_b[mg + 3];
      int ch = mi * 16 + quad * 4;
#pragma unroll
      for (int ni = 0; ni < 4; ++ni) {
        int lloc = wn + ni * 16 + col;
        float v0 = (acc[mi][ni][0] + b0) * sc;
        float v1 = (acc[mi][ni][1] + b1) * sc;
        float v2 = (acc[mi][ni][2] + b2) * sc;
        float v3 = (acc[mi][ni][3] + b3) * sc;
        int chs = ch ^ ((lloc & 7) << 3);
        *(uint2*)&Tile[lloc * 64 + chs] =
            make_uint2(pack_bf2(v0, v1), pack_bf2(v2, v3));
      }
    }
  } else {
    // v: Tile as [ch 64][l 128] (plain)
#pragma unroll
    for (int mi = 0; mi < 4; ++mi)
#pragma unroll
      for (int r = 0; r < 4; ++r) {
        int ch = mi * 16 + quad * 4 + r;
        float bias = qkv_b[m0 + wm + ch];
#pragma unroll
        for (int ni = 0; ni < 4; ++ni) {
          int lloc = wn + ni * 16 + col;
          Tile[ch * 128 + lloc] =
              (ushort_t)(__float_as_uint(acc[mi][ni][r] + bias) >> 16);
        }
      }
  }
  __syncthreads();
#pragma unroll
  for (int ci = 0; ci < 2; ++ci) {
    int cg = (m0 >> 6) + ci;
    int head = cg / 3, sel2 = cg % 3;
    int bh = b * NH + head;
    ushort_t* T2 = Smem + ci * 8192;
    if (sel2 < 2) {
      ushort_t* dst = (sel2 == 0) ? qT : kT;
      // raw copy: Tile image IS the pre-swizzled qT/kT image
#pragma unroll
      for (int it = 0; it < 4; ++it) {
        int idx = tid + it * 256;
        int l = idx >> 3, seg = idx & 7;
        uint4 v = *(const uint4*)&T2[l * 64 + seg * 8];
        *(uint4*)(dst + ((size_t)bh * LL + n0 + l) * CC / 8 * 0 +
                  ((size_t)bh * LL + n0 + l) * CH + seg * 8) = v;
      }
    } else {
      // v: write pre-swizzled within each 64-l block, keyed on ch&7
#pragma unroll
      for (int it = 0; it < 4; ++it) {
        int idx = tid + it * 256;
        int ch = idx >> 4, lseg = idx & 15;
        uint4 v = *(const uint4*)&T2[ch * 128 + lseg * 8];
        int g = lseg & 7, blk = lseg >> 3;
        *(uint4*)(vbuf + ((size_t)bh * CH + ch) * LL + n0 + blk * 64 +
                  ((g ^ (ch & 7)) << 3)) = v;
      }
    }
  }
}

// ---------------- Flash attention: 2-phase dbuf K/V + DMA staging ----------
__global__ __launch_bounds__(256) void attn_mfma_kernel(
    const ushort_t* __restrict__ qT, const ushort_t* __restrict__ kT,
    const ushort_t* __restrict__ vbuf, ushort_t* __restrict__ abuf) {
  // XCD-aware swizzle: all 16 t-tiles of one bh to the same XCD (L2 reuse)
  const int Bx = blockIdx.x;
  const int bh = (Bx & 7) * 8 + ((Bx >> 3) >> 4);
  const int t0g = ((Bx >> 3) & 15) * 64;
  const int b = bh >> 3, h = bh & 7;
  const int tid = threadIdx.x;
  const int w = tid >> 6, lane = tid & 63;
  const int col = lane & 15, quad = lane >> 4;
  const int strip = w * 16;
  __shared__ ushort_t Ps[64 * 64];       // P tiles (per-wave strips)
  __shared__ ushort_t Ksm[2][64 * 64];   // double-buffered K
  __shared__ ushort_t Vsm[2][64 * 64];   // double-buffered V

  const ushort_t* kbase = kT + (size_t)bh * LL * CH;
  const ushort_t* vbase = vbuf + (size_t)bh * CH * LL;
  const int eb = w * 1024 + lane * 8;

  // stage tile 0 (K: contiguous 8KB; V: 128B row segments)
#pragma unroll
  for (int i = 0; i < 2; ++i) {
    int ee = eb + i * 512;
    g2l16(kbase + ee, &Ksm[0][w * 1024 + i * 512]);
    g2l16(vbase + (size_t)(ee >> 6) * LL + (ee & 63),
          &Vsm[0][w * 1024 + i * 512]);
  }
  // Q fragments straight from (pre-swizzled) global -> registers
  const ushort_t* qtile = qT + ((size_t)bh * LL + t0g) * CH;
  short8 bq[2];
  bq[0] = *(const short8*)&qtile[swz(strip + col, quad * 8)];
  bq[1] = *(const short8*)&qtile[swz(strip + col, 32 + quad * 8)];

  float m_s = 0.f, lsum = 0.f;
  f32x4 oacc[4];
  f32x4 z = {0.f, 0.f, 0.f, 0.f};
#pragma unroll
  for (int ci = 0; ci < 4; ++ci) oacc[ci] = z;
  __syncthreads();  // implicit vmcnt(0): buf0 staged

  int cur = 0;
  for (int it = 0; it < 16; ++it) {
    // issue next tile's DMA; lands before the end-of-iter barrier
    if (it < 15) {
      const ushort_t* kn = kbase + (size_t)(it + 1) * 64 * CH;
      const ushort_t* vn = vbase + (it + 1) * 64;
#pragma unroll
      for (int i = 0; i < 2; ++i) {
        int ee = eb + i * 512;
        g2l16(kn + ee, &Ksm[cur ^ 1][w * 1024 + i * 512]);
        g2l16(vn + (size_t)(ee >> 6) * LL + (ee & 63),
              &Vsm[cur ^ 1][w * 1024 + i * 512]);
      }
    }
    const ushort_t* Kc = Ksm[cur];
    const ushort_t* Vc = Vsm[cur];
    // S^T[s][t] = K Q^T (q pre-scaled by 0.125*log2e)
    f32x4 sacc[4];
#pragma unroll
    for (int si = 0; si < 4; ++si) sacc[si] = z;
    __builtin_amdgcn_s_setprio(1);
#pragma unroll
    for (int kk = 0; kk < 2; ++kk)
#pragma unroll
      for (int si = 0; si < 4; ++si) {
        short8 ak = *(const short8*)&Kc[swz(si * 16 + col, kk * 32 + quad * 8)];
        sacc[si] = __builtin_amdgcn_mfma_f32_16x16x32_bf16(ak, bq[kk],
                                                           sacc[si], 0, 0, 0);
      }
    __builtin_amdgcn_s_setprio(0);
    if (it == 0) {  // freeze softmax shift at tile-0 max (range-safe)
      float mx = sacc[0][0];
#pragma unroll
      for (int si = 0; si < 4; ++si)
#pragma unroll
        for (int r = 0; r < 4; ++r) mx = fmaxf(mx, sacc[si][r]);
      mx = fmaxf(mx, __shfl_xor(mx, 16));
      mx = fmaxf(mx, __shfl_xor(mx, 32));
      m_s = mx;
    }
    // p = exp2(S' - m), accumulate l, pack into Ps ([t][s], swizzled)
#pragma unroll
    for (int si = 0; si < 4; ++si) {
      float p0 = __builtin_amdgcn_exp2f(sacc[si][0] - m_s);
      float p1 = __builtin_amdgcn_exp2f(sacc[si][1] - m_s);
      float p2 = __builtin_amdgcn_exp2f(sacc[si][2] - m_s);
      float p3 = __builtin_amdgcn_exp2f(sacc[si][3] - m_s);
      lsum += (p0 + p1) + (p2 + p3);
      int base = swz(strip + col, si * 16 + quad * 4);
      *(unsigned*)&Ps[base] = pack_bf2(p0, p1);
      *(unsigned*)&Ps[base + 2] = pack_bf2(p2, p3);
    }
    // O += P V^T
    __builtin_amdgcn_s_setprio(1);
#pragma unroll
    for (int kk = 0; kk < 2; ++kk) {
      short8 ap = *(const short8*)&Ps[swz(strip + col, kk * 32 + quad * 8)];
#pragma unroll
      for (int ci = 0; ci < 4; ++ci) {
        short8 bv = *(const short8*)&Vc[swz(ci * 16 + col, kk * 32 + quad * 8)];
        oacc[ci] = __builtin_amdgcn_mfma_f32_16x16x32_bf16(ap, bv, oacc[ci],
                                                           0, 0, 0);
      }
    }
    __builtin_amdgcn_s_setprio(0);
    __syncthreads();  // implicit vmcnt(0): next buf staged, cur consumed
    cur ^= 1;
  }
  // full row-sum l at t=strip+col; redistribute to t=strip+quad*4+r
  lsum += __shfl_xor(lsum, 16);
  lsum += __shfl_xor(lsum, 32);
  float linv[4];
#pragma unroll
  for (int r = 0; r < 4; ++r)
    linv[r] = 1.f / __shfl(lsum, (lane & 48) | (quad * 4 + r), 64);
#pragma unroll
  for (int r = 0; r < 4; ++r) {
    int l = t0g + strip + quad * 4 + r;
#pragma unroll
    for (int ci = 0; ci < 4; ++ci) {
      int cl = ci * 16 + col;
      // pre-swizzled abuf image (proj stages it linearly via DMA)
      int dcol = ((((cl >> 3) ^ (l & 7)) << 3) | (cl & 7));
      abuf[((size_t)b * LL + l) * CC + h * CH + dcol] =
          f2bf(oacc[ci][r] * linv[r]);
    }
  }
}

// ---------------- proj GEMM + bias + residual (DMA staging) ----------------
__global__ __launch_bounds__(256) void proj_mfma_kernel(
    const ushort_t* __restrict__ wp, const ushort_t* __restrict__ abuf,
    const float* __restrict__ proj_b, const float* __restrict__ x,
    float* __restrict__ out) {
  const int b = blockIdx.z;
  const int m0 = blockIdx.y * 64;
  const int n0 = blockIdx.x * 128;
  const int tid = threadIdx.x;
  const int w = tid >> 6, lane = tid & 63;
  const int col = lane & 15, quad = lane >> 4;
  const int wm = (w >> 1) * 32, wn = (w & 1) * 64;
  __shared__ ushort_t As[64 * 64];
  __shared__ ushort_t Bs[128 * 64];
  f32x4 acc[2][4];
  f32x4 z = {0.f, 0.f, 0.f, 0.f};
#pragma unroll
  for (int i = 0; i < 2; ++i)
#pragma unroll
    for (int j = 0; j < 4; ++j) acc[i][j] = z;

  const ushort_t* arow = wp + (size_t)m0 * CC;
  const ushort_t* brow = abuf + ((size_t)b * LL + n0) * CC;
  const int ea = w * 1024 + lane * 8;
  const int ebb = w * 2048 + lane * 8;

  for (int k0 = 0; k0 < CC; k0 += 64) {
    __syncthreads();
#pragma unroll
    for (int i = 0; i < 2; ++i) {
      int ee = ea + i * 512;
      g2l16(arow + (size_t)(ee >> 6) * CC + k0 + (ee & 63),
            As + (w * 1024 + i * 512));
    }
#pragma unroll
    for (int i = 0; i < 4; ++i) {
      int ee = ebb + i * 512;
      g2l16(brow + (size_t)(ee >> 6) * CC + k0 + (ee & 63),
            Bs + (w * 2048 + i * 512));
    }
    __syncthreads();
#pragma unroll
    for (int kk = 0; kk < 2; ++kk) {
      short8 af[2], bf[4];
#pragma unroll
      for (int mi = 0; mi < 2; ++mi)
        af[mi] = *(const short8*)&As[swz(wm + mi * 16 + col, kk * 32 + quad * 8)];
#pragma unroll
      for (int ni = 0; ni < 4; ++ni)
        bf[ni] = *(const short8*)&Bs[swz(wn + ni * 16 + col, kk * 32 + quad * 8)];
#pragma unroll
      for (int mi = 0; mi < 2; ++mi)
#pragma unroll
        for (int ni = 0; ni < 4; ++ni)
          acc[mi][ni] = __builtin_amdgcn_mfma_f32_16x16x32_bf16(
              af[mi], bf[ni], acc[mi][ni], 0, 0, 0);
    }
  }
#pragma unroll
  for (int mi = 0; mi < 2; ++mi)
#pragma unroll
    for (int r = 0; r < 4; ++r) {
      int o = m0 + wm + mi * 16 + quad * 4 + r;
      float bias = proj_b[o];
#pragma unroll
      for (int ni = 0; ni < 4; ++ni) {
        int l = n0 + wn + ni * 16 + col;
        size_t off = ((size_t)b * CC + o) * LL + l;
        out[off] = x[off] + bias + acc[mi][ni][r];
      }
    }
}

extern "C" void kernel_launch(void* const* d_in, const int* in_sizes, int n_in,
                              void* d_out, int out_size, void* d_ws,
                              size_t ws_size, hipStream_t stream) {
  const float* x = (const float*)d_in[0];
  const float* gn_w = (const float*)d_in[1];
  const float* gn_b = (const float*)d_in[2];
  const float* qkv_w = (const float*)d_in[3];
  const float* qkv_b = (const float*)d_in[4];
  const float* proj_w = (const float*)d_in[5];
  const float* proj_b = (const float*)d_in[6];
  float* out = (float*)d_out;

  char* ws = (char*)d_ws;
  float* s_bc = (float*)ws;
  float* t_bc = s_bc + BB * CC;
  ushort_t* wq = (ushort_t*)(t_bc + BB * CC);
  ushort_t* wp = wq + (size_t)3 * CC * CC;
  ushort_t* xnT = wp + (size_t)CC * CC;
  ushort_t* qT = xnT + (size_t)BB * LL * CC;
  ushort_t* kT = qT + (size_t)BB * NH * LL * CH;
  ushort_t* vb = kT + (size_t)BB * NH * LL * CH;
  ushort_t* abuf = vb + (size_t)BB * NH * LL * CH;

  pre_kernel<<<BB * GG + 1024, 256, 0, stream>>>(x, gn_w, gn_b, qkv_w, proj_w,
                                                 s_bc, t_bc, wq, wp);
  xnt_kernel<<<dim3(LL / 64, CC / 64, BB), 256, 0, stream>>>(x, s_bc, t_bc,
                                                             xnT);
  qkv_mfma_kernel<<<dim3(LL / 128, (3 * CC) / 128, BB), 256, 0, stream>>>(
      wq, xnT, qkv_b, qT, kT, vb);
  attn_mfma_kernel<<<dim3(1024), 256, 0, stream>>>(qT, kT, vb, abuf);
  proj_mfma_kernel<<<dim3(LL / 128, CC / 64, BB), 256, 0, stream>>>(
      wp, abuf, proj_b, x, out);
}

// Round 2
// 143.851 us; speedup vs baseline: 1.1873x; 1.0502x over previous
//
#include <hip/hip_runtime.h>
#include <math.h>

#define BB 8
#define CC 512
#define LL 1024
#define GG 32
#define CPG 16
#define NH 8
#define CH 64

typedef unsigned short ushort_t;
typedef __attribute__((ext_vector_type(8))) short short8;
typedef __attribute__((ext_vector_type(4))) float f32x4;

#define SCALE_Q 0.18033688f  // 0.125 * log2(e)

__device__ inline ushort_t f2bf(float f) {
  union { float f; unsigned u; } v;
  v.f = f;
  unsigned r = v.u + 0x7FFFu + ((v.u >> 16) & 1u);
  return (ushort_t)(r >> 16);
}

// pack two f32 -> two bf16 (truncate) in one v_perm_b32
__device__ inline unsigned pack_bf2(float lo, float hi) {
  return __builtin_amdgcn_perm(__float_as_uint(hi), __float_as_uint(lo),
                               0x07060302u);
}

// XOR-swizzled LDS index: rows of 64 bf16, 8-elt groups swizzled by row&7.
// Involution applied at producer (pre-swizzled global image) and at ds_read
// -> conflict-free fragment reads with LINEAR global_load_lds staging.
__device__ inline int swz(int r, int k) {
  return r * 64 + ((((k >> 3) ^ (r & 7)) << 3) | (k & 7));
}

// async 16B global->LDS (DMA). LDS dest = wave-uniform base + lane*16.
__device__ __forceinline__ void g2l16(const void* g, void* l) {
  __builtin_amdgcn_global_load_lds((const unsigned int*)g, (unsigned int*)l,
                                   16, 0, 0);
}

// ---------------- GroupNorm stats + weight convert (merged) ----------------
__global__ __launch_bounds__(256) void pre_kernel(
    const float* __restrict__ x, const float* __restrict__ gn_w,
    const float* __restrict__ gn_b, const float* __restrict__ qkv_w,
    const float* __restrict__ proj_w, float* __restrict__ s_bc,
    float* __restrict__ t_bc, ushort_t* __restrict__ wq,
    ushort_t* __restrict__ wp) {
  if (blockIdx.x < BB * GG) {
    int b = blockIdx.x / GG;
    int g = blockIdx.x % GG;
    const float4* xg4 =
        (const float4*)(x + ((size_t)b * CC + (size_t)g * CPG) * LL);
    float sum = 0.f, sq = 0.f;
#pragma unroll
    for (int i = 0; i < 16; ++i) {
      float4 v = xg4[threadIdx.x + i * 256];
      sum += (v.x + v.y) + (v.z + v.w);
      sq += (v.x * v.x + v.y * v.y) + (v.z * v.z + v.w * v.w);
    }
#pragma unroll
    for (int off = 32; off > 0; off >>= 1) {
      sum += __shfl_down(sum, off);
      sq += __shfl_down(sq, off);
    }
    __shared__ float red[8];
    __shared__ float st[2];
    int wave = threadIdx.x >> 6;
    if ((threadIdx.x & 63) == 0) {
      red[wave] = sum;
      red[4 + wave] = sq;
    }
    __syncthreads();
    if (threadIdx.x == 0) {
      float s = red[0] + red[1] + red[2] + red[3];
      float q = red[4] + red[5] + red[6] + red[7];
      float mean = s * (1.f / (CPG * LL));
      float var = q * (1.f / (CPG * LL)) - mean * mean;
      st[0] = mean;
      st[1] = rsqrtf(var + 1e-5f);
    }
    __syncthreads();
    if (threadIdx.x < CPG) {
      int c = g * CPG + threadIdx.x;
      float w = gn_w[c];
      float sc = st[1] * w;
      s_bc[b * CC + c] = sc;
      t_bc[b * CC + c] = gn_b[c] - st[0] * sc;
    }
  } else {
    int cb = blockIdx.x - BB * GG;
    int idx = (cb * 256 + threadIdx.x) * 4;
    const int N1 = 3 * CC * CC;
    float4 v;
    ushort_t* mat;
    int row, k;
    if (idx < N1) {
      v = *(const float4*)(qkv_w + idx);
      row = idx >> 9;
      k = idx & 511;
      mat = wq + (size_t)row * CC;
    } else {
      int j = idx - N1;
      v = *(const float4*)(proj_w + j);
      row = j >> 9;
      k = j & 511;
      mat = wp + (size_t)row * CC;
    }
    // pre-swizzle: 8-elt group ^= row&7 within each 64-col block
    int dcol = (k & ~63) | ((((k >> 3) & 7) ^ (row & 7)) << 3) | (k & 7);
    unsigned lo = f2bf(v.x) | ((unsigned)f2bf(v.y) << 16);
    unsigned hi = f2bf(v.z) | ((unsigned)f2bf(v.w) << 16);
    *(uint2*)(mat + dcol) = make_uint2(lo, hi);
  }
}

// ---------------- GN apply + transpose -> xnT[b][l][c] bf16 (pre-swizzled) --
__global__ __launch_bounds__(256) void xnt_kernel(
    const float* __restrict__ x, const float* __restrict__ s_bc,
    const float* __restrict__ t_bc, ushort_t* __restrict__ xnT) {
  const int b = blockIdx.z;
  const int c0 = blockIdx.y * 64;
  const int l0 = blockIdx.x * 64;
  const int tid = threadIdx.x;
  __shared__ ushort_t Ts[64 * 72];
#pragma unroll
  for (int r4 = 0; r4 < 4; ++r4) {
    int c_local = (tid >> 4) + r4 * 16;
    int l_local = (tid & 15) * 4;
    int c = c0 + c_local;
    float sc = s_bc[b * CC + c], sh = t_bc[b * CC + c];
    float4 v = *(const float4*)(x + ((size_t)b * CC + c) * LL + l0 + l_local);
    float vv[4] = {v.x, v.y, v.z, v.w};
#pragma unroll
    for (int dl = 0; dl < 4; ++dl) {
      int l = l_local + dl;
      int cs = c_local ^ (((l >> 2) & 7) << 3);
      Ts[l * 72 + cs] = f2bf(vv[dl] * sc + sh);
    }
  }
  __syncthreads();
#pragma unroll
  for (int rep = 0; rep < 2; ++rep) {
    int gid = tid + rep * 256;
    int l = gid >> 3, seg = gid & 7;
    uint4 v = *(const uint4*)&Ts[l * 72 + ((seg * 8) ^ (((l >> 2) & 7) << 3))];
    // pre-swizzled global image: group seg -> seg ^ (l&7)
    *(uint4*)(xnT + ((size_t)b * LL + l0 + l) * CC + c0 +
              ((seg ^ (l & 7)) << 3)) = v;
  }
}

// ---------------- QKV GEMM: 192x128 tile, 6 waves, 2-phase dbuf DMA --------
// Block y owns head y's q,k,v chunks (192 = 3 x 64 rows) for one n-range.
__global__ __launch_bounds__(384, 3) void qkv_mfma_kernel(
    const ushort_t* __restrict__ wq, const ushort_t* __restrict__ xnT,
    const float* __restrict__ qkv_b, ushort_t* __restrict__ qT,
    ushort_t* __restrict__ kT, ushort_t* __restrict__ vbuf) {
  const int b = blockIdx.z;
  const int m0 = blockIdx.y * 192;
  const int n0 = blockIdx.x * 128;
  const int tid = threadIdx.x;
  const int w = tid >> 6, lane = tid & 63;
  const int col = lane & 15, quad = lane >> 4;
  const int wm = (w >> 1) * 64, wn = (w & 1) * 64;
  // 80KB: 2 buffers x (A 24KB | B 16KB); epilogue reuses as 3x16KB tiles
  __shared__ ushort_t Smem[2 * 20480];
  f32x4 acc[4][4];
  f32x4 z = {0.f, 0.f, 0.f, 0.f};
#pragma unroll
  for (int i = 0; i < 4; ++i)
#pragma unroll
    for (int j = 0; j < 4; ++j) acc[i][j] = z;

  const ushort_t* arow = wq + (size_t)m0 * CC;
  const ushort_t* brow = xnT + ((size_t)b * LL + n0) * CC;

  auto stage = [&](int bb, int k0) {
    ushort_t* As = Smem + bb * 20480;
    ushort_t* Bs = As + 12288;
#pragma unroll
    for (int j = 0; j < 4; ++j) {
      int e = (j * 6 + w) * 512 + lane * 8;
      g2l16(arow + (size_t)(e >> 6) * CC + k0 + (e & 63),
            As + (j * 6 + w) * 512);
    }
    if (w < 4) {
#pragma unroll
      for (int j = 0; j < 4; ++j) {
        int e = (j * 4 + w) * 512 + lane * 8;
        g2l16(brow + (size_t)(e >> 6) * CC + k0 + (e & 63),
              Bs + (j * 4 + w) * 512);
      }
    }
  };

  stage(0, 0);
  __syncthreads();  // drain prologue DMA
  int cur = 0;
  for (int step = 0; step < 8; ++step) {
    if (step < 7) stage(cur ^ 1, (step + 1) * 64);  // prefetch next K-step
    const ushort_t* As = Smem + cur * 20480;
    const ushort_t* Bs = As + 12288;
#pragma unroll
    for (int kk = 0; kk < 2; ++kk) {
      short8 af[4], bf[4];
#pragma unroll
      for (int mi = 0; mi < 4; ++mi)
        af[mi] = *(const short8*)&As[swz(wm + mi * 16 + col, kk * 32 + quad * 8)];
#pragma unroll
      for (int ni = 0; ni < 4; ++ni)
        bf[ni] = *(const short8*)&Bs[swz(wn + ni * 16 + col, kk * 32 + quad * 8)];
#pragma unroll
      for (int mi = 0; mi < 4; ++mi)
#pragma unroll
        for (int ni = 0; ni < 4; ++ni)
          acc[mi][ni] = __builtin_amdgcn_mfma_f32_16x16x32_bf16(
              af[mi], bf[ni], acc[mi][ni], 0, 0, 0);
    }
    __syncthreads();  // drains prefetch (hidden under MFMA) + WAR protect
    cur ^= 1;
  }
  // ---- epilogue: wave (w>>1) writes chunk ci = w>>1 (0=q,1=k,2=v) ----
  const int ci_w = w >> 1;
  ushort_t* Tile = Smem + ci_w * 8192;
  if (ci_w < 2) {
    // q/k: Tile as [l 128][ch 64], xor-swizzled == pre-swizzled global image
    const float sc = (ci_w == 0) ? SCALE_Q : 1.f;
#pragma unroll
    for (int mi = 0; mi < 4; ++mi) {
      int mg = m0 + wm + mi * 16 + quad * 4;
      float b0 = qkv_b[mg + 0], b1 = qkv_b[mg + 1];
      float b2 = qkv_b[mg + 2], b3 = qkv_b[mg + 3];
      int ch = mi * 16 + quad * 4;
#pragma unroll
      for (int ni = 0; ni < 4; ++ni) {
        int lloc = wn + ni * 16 + col;
        float v0 = (acc[mi][ni][0] + b0) * sc;
        float v1 = (acc[mi][ni][1] + b1) * sc;
        float v2 = (acc[mi][ni][2] + b2) * sc;
        float v3 = (acc[mi][ni][3] + b3) * sc;
        int chs = ch ^ ((lloc & 7) << 3);
        *(uint2*)&Tile[lloc * 64 + chs] =
            make_uint2(pack_bf2(v0, v1), pack_bf2(v2, v3));
      }
    }
  } else {
    // v: Tile as [ch 64][l 128] (plain)
#pragma unroll
    for (int mi = 0; mi < 4; ++mi)
#pragma unroll
      for (int r = 0; r < 4; ++r) {
        int ch = mi * 16 + quad * 4 + r;
        float bias = qkv_b[m0 + wm + ch];
#pragma unroll
        for (int ni = 0; ni < 4; ++ni) {
          int lloc = wn + ni * 16 + col;
          Tile[ch * 128 + lloc] =
              (ushort_t)(__float_as_uint(acc[mi][ni][r] + bias) >> 16);
        }
      }
  }
  __syncthreads();
  const int head = blockIdx.y;
  const int bh = b * NH + head;
#pragma unroll
  for (int ci = 0; ci < 3; ++ci) {
    ushort_t* T2 = Smem + ci * 8192;
    if (ci < 2) {
      ushort_t* dst = (ci == 0) ? qT : kT;
#pragma unroll
      for (int it = 0; it < 3; ++it) {
        int idx = tid + it * 384;
        if (idx < 1024) {
          int l = idx >> 3, seg = idx & 7;
          uint4 v = *(const uint4*)&T2[l * 64 + seg * 8];
          *(uint4*)(dst + ((size_t)bh * LL + n0 + l) * CH + seg * 8) = v;
        }
      }
    } else {
#pragma unroll
      for (int it = 0; it < 3; ++it) {
        int idx = tid + it * 384;
        if (idx < 1024) {
          int ch = idx >> 4, lseg = idx & 15;
          uint4 v = *(const uint4*)&T2[ch * 128 + lseg * 8];
          int g = lseg & 7, blk = lseg >> 3;
          *(uint4*)(vbuf + ((size_t)bh * CH + ch) * LL + n0 + blk * 64 +
                    ((g ^ (ch & 7)) << 3)) = v;
        }
      }
    }
  }
}

// ---------------- Flash attention: 2-phase dbuf K/V + DMA staging ----------
__global__ __launch_bounds__(256) void attn_mfma_kernel(
    const ushort_t* __restrict__ qT, const ushort_t* __restrict__ kT,
    const ushort_t* __restrict__ vbuf, ushort_t* __restrict__ abuf) {
  // XCD-aware swizzle: all 16 t-tiles of one bh to the same XCD (L2 reuse)
  const int Bx = blockIdx.x;
  const int bh = (Bx & 7) * 8 + ((Bx >> 3) >> 4);
  const int t0g = ((Bx >> 3) & 15) * 64;
  const int b = bh >> 3, h = bh & 7;
  const int tid = threadIdx.x;
  const int w = tid >> 6, lane = tid & 63;
  const int col = lane & 15, quad = lane >> 4;
  const int strip = w * 16;
  __shared__ ushort_t Ps[64 * 64];       // P tiles (per-wave strips)
  __shared__ ushort_t Ksm[2][64 * 64];   // double-buffered K
  __shared__ ushort_t Vsm[2][64 * 64];   // double-buffered V

  const ushort_t* kbase = kT + (size_t)bh * LL * CH;
  const ushort_t* vbase = vbuf + (size_t)bh * CH * LL;
  const int eb = w * 1024 + lane * 8;

  // stage tile 0 (K: contiguous 8KB; V: 128B row segments)
#pragma unroll
  for (int i = 0; i < 2; ++i) {
    int ee = eb + i * 512;
    g2l16(kbase + ee, &Ksm[0][w * 1024 + i * 512]);
    g2l16(vbase + (size_t)(ee >> 6) * LL + (ee & 63),
          &Vsm[0][w * 1024 + i * 512]);
  }
  // Q fragments straight from (pre-swizzled) global -> registers
  const ushort_t* qtile = qT + ((size_t)bh * LL + t0g) * CH;
  short8 bq[2];
  bq[0] = *(const short8*)&qtile[swz(strip + col, quad * 8)];
  bq[1] = *(const short8*)&qtile[swz(strip + col, 32 + quad * 8)];

  float m_s = 0.f, lsum = 0.f;
  f32x4 oacc[4];
  f32x4 z = {0.f, 0.f, 0.f, 0.f};
#pragma unroll
  for (int ci = 0; ci < 4; ++ci) oacc[ci] = z;
  __syncthreads();  // implicit vmcnt(0): buf0 staged

  int cur = 0;
  for (int it = 0; it < 16; ++it) {
    // issue next tile's DMA; drained by end-of-iter barrier (hidden)
    if (it < 15) {
      const ushort_t* kn = kbase + (size_t)(it + 1) * 64 * CH;
      const ushort_t* vn = vbase + (it + 1) * 64;
#pragma unroll
      for (int i = 0; i < 2; ++i) {
        int ee = eb + i * 512;
        g2l16(kn + ee, &Ksm[cur ^ 1][w * 1024 + i * 512]);
        g2l16(vn + (size_t)(ee >> 6) * LL + (ee & 63),
              &Vsm[cur ^ 1][w * 1024 + i * 512]);
      }
    }
    const ushort_t* Kc = Ksm[cur];
    const ushort_t* Vc = Vsm[cur];
    // S^T[s][t] = K Q^T (q pre-scaled by 0.125*log2e)
    f32x4 sacc[4];
#pragma unroll
    for (int si = 0; si < 4; ++si) sacc[si] = z;
    __builtin_amdgcn_s_setprio(1);
#pragma unroll
    for (int kk = 0; kk < 2; ++kk)
#pragma unroll
      for (int si = 0; si < 4; ++si) {
        short8 ak = *(const short8*)&Kc[swz(si * 16 + col, kk * 32 + quad * 8)];
        sacc[si] = __builtin_amdgcn_mfma_f32_16x16x32_bf16(ak, bq[kk],
                                                           sacc[si], 0, 0, 0);
      }
    __builtin_amdgcn_s_setprio(0);
    if (it == 0) {  // freeze softmax shift at tile-0 max (range-safe)
      float mx = sacc[0][0];
#pragma unroll
      for (int si = 0; si < 4; ++si)
#pragma unroll
        for (int r = 0; r < 4; ++r) mx = fmaxf(mx, sacc[si][r]);
      mx = fmaxf(mx, __shfl_xor(mx, 16));
      mx = fmaxf(mx, __shfl_xor(mx, 32));
      m_s = mx;
    }
    // p = exp2(S' - m), accumulate l, pack into Ps ([t][s], swizzled)
#pragma unroll
    for (int si = 0; si < 4; ++si) {
      float p0 = __builtin_amdgcn_exp2f(sacc[si][0] - m_s);
      float p1 = __builtin_amdgcn_exp2f(sacc[si][1] - m_s);
      float p2 = __builtin_amdgcn_exp2f(sacc[si][2] - m_s);
      float p3 = __builtin_amdgcn_exp2f(sacc[si][3] - m_s);
      lsum += (p0 + p1) + (p2 + p3);
      int base = swz(strip + col, si * 16 + quad * 4);
      *(unsigned*)&Ps[base] = pack_bf2(p0, p1);
      *(unsigned*)&Ps[base + 2] = pack_bf2(p2, p3);
    }
    // O += P V^T
    __builtin_amdgcn_s_setprio(1);
#pragma unroll
    for (int kk = 0; kk < 2; ++kk) {
      short8 ap = *(const short8*)&Ps[swz(strip + col, kk * 32 + quad * 8)];
#pragma unroll
      for (int ci = 0; ci < 4; ++ci) {
        short8 bv = *(const short8*)&Vc[swz(ci * 16 + col, kk * 32 + quad * 8)];
        oacc[ci] = __builtin_amdgcn_mfma_f32_16x16x32_bf16(ap, bv, oacc[ci],
                                                           0, 0, 0);
      }
    }
    __builtin_amdgcn_s_setprio(0);
    __syncthreads();  // implicit vmcnt(0): next buf staged, cur consumed
    cur ^= 1;
  }
  // full row-sum l at t=strip+col; redistribute to t=strip+quad*4+r
  lsum += __shfl_xor(lsum, 16);
  lsum += __shfl_xor(lsum, 32);
  float linv[4];
#pragma unroll
  for (int r = 0; r < 4; ++r)
    linv[r] = 1.f / __shfl(lsum, (lane & 48) | (quad * 4 + r), 64);
#pragma unroll
  for (int r = 0; r < 4; ++r) {
    int l = t0g + strip + quad * 4 + r;
#pragma unroll
    for (int ci = 0; ci < 4; ++ci) {
      int cl = ci * 16 + col;
      // pre-swizzled abuf image (proj stages it linearly via DMA)
      int dcol = ((((cl >> 3) ^ (l & 7)) << 3) | (cl & 7));
      abuf[((size_t)b * LL + l) * CC + h * CH + dcol] =
          f2bf(oacc[ci][r] * linv[r]);
    }
  }
}

// ---------------- proj GEMM + bias + residual: 2-phase dbuf DMA ------------
__global__ __launch_bounds__(256) void proj_mfma_kernel(
    const ushort_t* __restrict__ wp, const ushort_t* __restrict__ abuf,
    const float* __restrict__ proj_b, const float* __restrict__ x,
    float* __restrict__ out) {
  const int b = blockIdx.z;
  const int m0 = blockIdx.y * 64;
  const int n0 = blockIdx.x * 128;
  const int tid = threadIdx.x;
  const int w = tid >> 6, lane = tid & 63;
  const int col = lane & 15, quad = lane >> 4;
  const int wm = (w >> 1) * 32, wn = (w & 1) * 64;
  // 48KB: 2 buffers x (A 8KB | B 16KB)
  __shared__ ushort_t Smem[2 * 12288];
  f32x4 acc[2][4];
  f32x4 z = {0.f, 0.f, 0.f, 0.f};
#pragma unroll
  for (int i = 0; i < 2; ++i)
#pragma unroll
    for (int j = 0; j < 4; ++j) acc[i][j] = z;

  const ushort_t* arow = wp + (size_t)m0 * CC;
  const ushort_t* brow = abuf + ((size_t)b * LL + n0) * CC;

  auto stage = [&](int bb, int k0) {
    ushort_t* As = Smem + bb * 12288;
    ushort_t* Bs = As + 4096;
#pragma unroll
    for (int j = 0; j < 2; ++j) {
      int e = (j * 4 + w) * 512 + lane * 8;
      g2l16(arow + (size_t)(e >> 6) * CC + k0 + (e & 63),
            As + (j * 4 + w) * 512);
    }
#pragma unroll
    for (int j = 0; j < 4; ++j) {
      int e = (j * 4 + w) * 512 + lane * 8;
      g2l16(brow + (size_t)(e >> 6) * CC + k0 + (e & 63),
            Bs + (j * 4 + w) * 512);
    }
  };

  stage(0, 0);
  __syncthreads();
  int cur = 0;
  for (int step = 0; step < 8; ++step) {
    if (step < 7) stage(cur ^ 1, (step + 1) * 64);
    const ushort_t* As = Smem + cur * 12288;
    const ushort_t* Bs = As + 4096;
#pragma unroll
    for (int kk = 0; kk < 2; ++kk) {
      short8 af[2], bf[4];
#pragma unroll
      for (int mi = 0; mi < 2; ++mi)
        af[mi] = *(const short8*)&As[swz(wm + mi * 16 + col, kk * 32 + quad * 8)];
#pragma unroll
      for (int ni = 0; ni < 4; ++ni)
        bf[ni] = *(const short8*)&Bs[swz(wn + ni * 16 + col, kk * 32 + quad * 8)];
#pragma unroll
      for (int mi = 0; mi < 2; ++mi)
#pragma unroll
        for (int ni = 0; ni < 4; ++ni)
          acc[mi][ni] = __builtin_amdgcn_mfma_f32_16x16x32_bf16(
              af[mi], bf[ni], acc[mi][ni], 0, 0, 0);
    }
    __syncthreads();
    cur ^= 1;
  }
#pragma unroll
  for (int mi = 0; mi < 2; ++mi)
#pragma unroll
    for (int r = 0; r < 4; ++r) {
      int o = m0 + wm + mi * 16 + quad * 4 + r;
      float bias = proj_b[o];
#pragma unroll
      for (int ni = 0; ni < 4; ++ni) {
        int l = n0 + wn + ni * 16 + col;
        size_t off = ((size_t)b * CC + o) * LL + l;
        out[off] = x[off] + bias + acc[mi][ni][r];
      }
    }
}

extern "C" void kernel_launch(void* const* d_in, const int* in_sizes, int n_in,
                              void* d_out, int out_size, void* d_ws,
                              size_t ws_size, hipStream_t stream) {
  const float* x = (const float*)d_in[0];
  const float* gn_w = (const float*)d_in[1];
  const float* gn_b = (const float*)d_in[2];
  const float* qkv_w = (const float*)d_in[3];
  const float* qkv_b = (const float*)d_in[4];
  const float* proj_w = (const float*)d_in[5];
  const float* proj_b = (const float*)d_in[6];
  float* out = (float*)d_out;

  char* ws = (char*)d_ws;
  float* s_bc = (float*)ws;
  float* t_bc = s_bc + BB * CC;
  ushort_t* wq = (ushort_t*)(t_bc + BB * CC);
  ushort_t* wp = wq + (size_t)3 * CC * CC;
  ushort_t* xnT = wp + (size_t)CC * CC;
  ushort_t* qT = xnT + (size_t)BB * LL * CC;
  ushort_t* kT = qT + (size_t)BB * NH * LL * CH;
  ushort_t* vb = kT + (size_t)BB * NH * LL * CH;
  ushort_t* abuf = vb + (size_t)BB * NH * LL * CH;

  pre_kernel<<<BB * GG + 1024, 256, 0, stream>>>(x, gn_w, gn_b, qkv_w, proj_w,
                                                 s_bc, t_bc, wq, wp);
  xnt_kernel<<<dim3(LL / 64, CC / 64, BB), 256, 0, stream>>>(x, s_bc, t_bc,
                                                             xnT);
  qkv_mfma_kernel<<<dim3(LL / 128, 1536 / 192, BB), 384, 0, stream>>>(
      wq, xnT, qkv_b, qT, kT, vb);
  attn_mfma_kernel<<<dim3(1024), 256, 0, stream>>>(qT, kT, vb, abuf);
  proj_mfma_kernel<<<dim3(LL / 128, CC / 64, BB), 256, 0, stream>>>(
      wp, abuf, proj_b, x, out);
}

// Round 3
// 139.521 us; speedup vs baseline: 1.2241x; 1.0310x over previous
//
#include <hip/hip_runtime.h>
#include <math.h>

#define BB 8
#define CC 512
#define LL 1024
#define GG 32
#define CPG 16
#define NH 8
#define CH 64

typedef unsigned short ushort_t;
typedef __attribute__((ext_vector_type(8))) short short8;
typedef __attribute__((ext_vector_type(4))) float f32x4;
typedef __attribute__((ext_vector_type(16))) float f32x16;

#define SCALE_Q 0.18033688f  // 0.125 * log2(e)

__device__ inline ushort_t f2bf(float f) {
  union { float f; unsigned u; } v;
  v.f = f;
  unsigned r = v.u + 0x7FFFu + ((v.u >> 16) & 1u);
  return (ushort_t)(r >> 16);
}

// pack two f32 -> two bf16 (truncate) in one v_perm_b32
__device__ inline unsigned pack_bf2(float lo, float hi) {
  return __builtin_amdgcn_perm(__float_as_uint(hi), __float_as_uint(lo),
                               0x07060302u);
}

// XOR-swizzled LDS index: rows of 64 bf16, 8-elt groups swizzled by row&7.
// Involution applied at producer (pre-swizzled global image) and at ds_read
// -> conflict-free fragment reads with LINEAR global_load_lds staging.
__device__ inline int swz(int r, int k) {
  return r * 64 + ((((k >> 3) ^ (r & 7)) << 3) | (k & 7));
}

// async 16B global->LDS (DMA). LDS dest = wave-uniform base + lane*16.
__device__ __forceinline__ void g2l16(const void* g, void* l) {
  __builtin_amdgcn_global_load_lds((const unsigned int*)g, (unsigned int*)l,
                                   16, 0, 0);
}

// ---------------- GroupNorm stats + weight convert (merged) ----------------
__global__ __launch_bounds__(256) void pre_kernel(
    const float* __restrict__ x, const float* __restrict__ gn_w,
    const float* __restrict__ gn_b, const float* __restrict__ qkv_w,
    const float* __restrict__ proj_w, float* __restrict__ s_bc,
    float* __restrict__ t_bc, ushort_t* __restrict__ wq,
    ushort_t* __restrict__ wp) {
  if (blockIdx.x < BB * GG) {
    int b = blockIdx.x / GG;
    int g = blockIdx.x % GG;
    const float4* xg4 =
        (const float4*)(x + ((size_t)b * CC + (size_t)g * CPG) * LL);
    float sum = 0.f, sq = 0.f;
#pragma unroll
    for (int i = 0; i < 16; ++i) {
      float4 v = xg4[threadIdx.x + i * 256];
      sum += (v.x + v.y) + (v.z + v.w);
      sq += (v.x * v.x + v.y * v.y) + (v.z * v.z + v.w * v.w);
    }
#pragma unroll
    for (int off = 32; off > 0; off >>= 1) {
      sum += __shfl_down(sum, off);
      sq += __shfl_down(sq, off);
    }
    __shared__ float red[8];
    __shared__ float st[2];
    int wave = threadIdx.x >> 6;
    if ((threadIdx.x & 63) == 0) {
      red[wave] = sum;
      red[4 + wave] = sq;
    }
    __syncthreads();
    if (threadIdx.x == 0) {
      float s = red[0] + red[1] + red[2] + red[3];
      float q = red[4] + red[5] + red[6] + red[7];
      float mean = s * (1.f / (CPG * LL));
      float var = q * (1.f / (CPG * LL)) - mean * mean;
      st[0] = mean;
      st[1] = rsqrtf(var + 1e-5f);
    }
    __syncthreads();
    if (threadIdx.x < CPG) {
      int c = g * CPG + threadIdx.x;
      float w = gn_w[c];
      float sc = st[1] * w;
      s_bc[b * CC + c] = sc;
      t_bc[b * CC + c] = gn_b[c] - st[0] * sc;
    }
  } else {
    int cb = blockIdx.x - BB * GG;
    int idx = (cb * 256 + threadIdx.x) * 4;
    const int N1 = 3 * CC * CC;
    float4 v;
    ushort_t* mat;
    int row, k;
    if (idx < N1) {
      v = *(const float4*)(qkv_w + idx);
      row = idx >> 9;
      k = idx & 511;
      mat = wq + (size_t)row * CC;
    } else {
      int j = idx - N1;
      v = *(const float4*)(proj_w + j);
      row = j >> 9;
      k = j & 511;
      mat = wp + (size_t)row * CC;
    }
    // pre-swizzle: 8-elt group ^= row&7 within each 64-col block
    int dcol = (k & ~63) | ((((k >> 3) & 7) ^ (row & 7)) << 3) | (k & 7);
    unsigned lo = f2bf(v.x) | ((unsigned)f2bf(v.y) << 16);
    unsigned hi = f2bf(v.z) | ((unsigned)f2bf(v.w) << 16);
    *(uint2*)(mat + dcol) = make_uint2(lo, hi);
  }
}

// ---------------- GN apply + transpose -> xnT[b][l][c] bf16 (pre-swizzled) --
__global__ __launch_bounds__(256) void xnt_kernel(
    const float* __restrict__ x, const float* __restrict__ s_bc,
    const float* __restrict__ t_bc, ushort_t* __restrict__ xnT) {
  const int b = blockIdx.z;
  const int c0 = blockIdx.y * 64;
  const int l0 = blockIdx.x * 64;
  const int tid = threadIdx.x;
  __shared__ ushort_t Ts[64 * 72];
#pragma unroll
  for (int r4 = 0; r4 < 4; ++r4) {
    int c_local = (tid >> 4) + r4 * 16;
    int l_local = (tid & 15) * 4;
    int c = c0 + c_local;
    float sc = s_bc[b * CC + c], sh = t_bc[b * CC + c];
    float4 v = *(const float4*)(x + ((size_t)b * CC + c) * LL + l0 + l_local);
    float vv[4] = {v.x, v.y, v.z, v.w};
#pragma unroll
    for (int dl = 0; dl < 4; ++dl) {
      int l = l_local + dl;
      int cs = c_local ^ (((l >> 2) & 7) << 3);
      Ts[l * 72 + cs] = f2bf(vv[dl] * sc + sh);
    }
  }
  __syncthreads();
#pragma unroll
  for (int rep = 0; rep < 2; ++rep) {
    int gid = tid + rep * 256;
    int l = gid >> 3, seg = gid & 7;
    uint4 v = *(const uint4*)&Ts[l * 72 + ((seg * 8) ^ (((l >> 2) & 7) << 3))];
    // pre-swizzled global image: group seg -> seg ^ (l&7)
    *(uint4*)(xnT + ((size_t)b * LL + l0 + l) * CC + c0 +
              ((seg ^ (l & 7)) << 3)) = v;
  }
}

// ---------------- QKV GEMM: 192x128 tile, 6 waves, 2-phase dbuf DMA --------
__global__ __launch_bounds__(384, 3) void qkv_mfma_kernel(
    const ushort_t* __restrict__ wq, const ushort_t* __restrict__ xnT,
    const float* __restrict__ qkv_b, ushort_t* __restrict__ qT,
    ushort_t* __restrict__ kT, ushort_t* __restrict__ vbuf) {
  const int b = blockIdx.z;
  const int m0 = blockIdx.y * 192;
  const int n0 = blockIdx.x * 128;
  const int tid = threadIdx.x;
  const int w = tid >> 6, lane = tid & 63;
  const int col = lane & 15, quad = lane >> 4;
  const int wm = (w >> 1) * 64, wn = (w & 1) * 64;
  __shared__ ushort_t Smem[2 * 20480];
  f32x4 acc[4][4];
  f32x4 z = {0.f, 0.f, 0.f, 0.f};
#pragma unroll
  for (int i = 0; i < 4; ++i)
#pragma unroll
    for (int j = 0; j < 4; ++j) acc[i][j] = z;

  const ushort_t* arow = wq + (size_t)m0 * CC;
  const ushort_t* brow = xnT + ((size_t)b * LL + n0) * CC;

  auto stage = [&](int bb, int k0) {
    ushort_t* As = Smem + bb * 20480;
    ushort_t* Bs = As + 12288;
#pragma unroll
    for (int j = 0; j < 4; ++j) {
      int e = (j * 6 + w) * 512 + lane * 8;
      g2l16(arow + (size_t)(e >> 6) * CC + k0 + (e & 63),
            As + (j * 6 + w) * 512);
    }
    if (w < 4) {
#pragma unroll
      for (int j = 0; j < 4; ++j) {
        int e = (j * 4 + w) * 512 + lane * 8;
        g2l16(brow + (size_t)(e >> 6) * CC + k0 + (e & 63),
              Bs + (j * 4 + w) * 512);
      }
    }
  };

  stage(0, 0);
  __syncthreads();
  int cur = 0;
  for (int step = 0; step < 8; ++step) {
    if (step < 7) stage(cur ^ 1, (step + 1) * 64);
    const ushort_t* As = Smem + cur * 20480;
    const ushort_t* Bs = As + 12288;
#pragma unroll
    for (int kk = 0; kk < 2; ++kk) {
      short8 af[4], bf[4];
#pragma unroll
      for (int mi = 0; mi < 4; ++mi)
        af[mi] = *(const short8*)&As[swz(wm + mi * 16 + col, kk * 32 + quad * 8)];
#pragma unroll
      for (int ni = 0; ni < 4; ++ni)
        bf[ni] = *(const short8*)&Bs[swz(wn + ni * 16 + col, kk * 32 + quad * 8)];
#pragma unroll
      for (int mi = 0; mi < 4; ++mi)
#pragma unroll
        for (int ni = 0; ni < 4; ++ni)
          acc[mi][ni] = __builtin_amdgcn_mfma_f32_16x16x32_bf16(
              af[mi], bf[ni], acc[mi][ni], 0, 0, 0);
    }
    __syncthreads();
    cur ^= 1;
  }
  // ---- epilogue: wave pair (w>>1) writes chunk ci = w>>1 (0=q,1=k,2=v) ----
  const int ci_w = w >> 1;
  ushort_t* Tile = Smem + ci_w * 8192;
  if (ci_w < 2) {
    const float sc = (ci_w == 0) ? SCALE_Q : 1.f;
#pragma unroll
    for (int mi = 0; mi < 4; ++mi) {
      int mg = m0 + wm + mi * 16 + quad * 4;
      float b0 = qkv_b[mg + 0], b1 = qkv_b[mg + 1];
      float b2 = qkv_b[mg + 2], b3 = qkv_b[mg + 3];
      int ch = mi * 16 + quad * 4;
#pragma unroll
      for (int ni = 0; ni < 4; ++ni) {
        int lloc = wn + ni * 16 + col;
        float v0 = (acc[mi][ni][0] + b0) * sc;
        float v1 = (acc[mi][ni][1] + b1) * sc;
        float v2 = (acc[mi][ni][2] + b2) * sc;
        float v3 = (acc[mi][ni][3] + b3) * sc;
        int chs = ch ^ ((lloc & 7) << 3);
        *(uint2*)&Tile[lloc * 64 + chs] =
            make_uint2(pack_bf2(v0, v1), pack_bf2(v2, v3));
      }
    }
  } else {
#pragma unroll
    for (int mi = 0; mi < 4; ++mi)
#pragma unroll
      for (int r = 0; r < 4; ++r) {
        int ch = mi * 16 + quad * 4 + r;
        float bias = qkv_b[m0 + wm + ch];
#pragma unroll
        for (int ni = 0; ni < 4; ++ni) {
          int lloc = wn + ni * 16 + col;
          Tile[ch * 128 + lloc] =
              (ushort_t)(__float_as_uint(acc[mi][ni][r] + bias) >> 16);
        }
      }
  }
  __syncthreads();
  const int head = blockIdx.y;
  const int bh = b * NH + head;
#pragma unroll
  for (int ci = 0; ci < 3; ++ci) {
    ushort_t* T2 = Smem + ci * 8192;
    if (ci < 2) {
      ushort_t* dst = (ci == 0) ? qT : kT;
#pragma unroll
      for (int it = 0; it < 3; ++it) {
        int idx = tid + it * 384;
        if (idx < 1024) {
          int l = idx >> 3, seg = idx & 7;
          uint4 v = *(const uint4*)&T2[l * 64 + seg * 8];
          *(uint4*)(dst + ((size_t)bh * LL + n0 + l) * CH + seg * 8) = v;
        }
      }
    } else {
#pragma unroll
      for (int it = 0; it < 3; ++it) {
        int idx = tid + it * 384;
        if (idx < 1024) {
          int ch = idx >> 4, lseg = idx & 15;
          uint4 v = *(const uint4*)&T2[ch * 128 + lseg * 8];
          int g = lseg & 7, blk = lseg >> 3;
          *(uint4*)(vbuf + ((size_t)bh * CH + ch) * LL + n0 + blk * 64 +
                    ((g ^ (ch & 7)) << 3)) = v;
        }
      }
    }
  }
}

// ---------------- Flash attention: 32x32 MFMA, in-register P ---------------
// Block: 128 t x all s; 4 waves each own a 32-t strip. No P LDS round-trip:
// S^T via mfma(K, Q) leaves lane with full P row (half s per lane-half);
// permlane32_swap assembles PV A-fragments in-register (T12).
__global__ __launch_bounds__(256) void attn_mfma_kernel(
    const ushort_t* __restrict__ qT, const ushort_t* __restrict__ kT,
    const ushort_t* __restrict__ vbuf, ushort_t* __restrict__ abuf) {
  // XCD-aware swizzle: all 8 t-tiles of one bh to the same XCD (L2 reuse)
  const int Bx = blockIdx.x;
  const int bh = (Bx & 7) * 8 + ((Bx >> 3) >> 3);
  const int t0g = ((Bx >> 3) & 7) * 128;
  const int b = bh >> 3, h = bh & 7;
  const int tid = threadIdx.x;
  const int w = tid >> 6, lane = tid & 63;
  const int ln31 = lane & 31, hi = lane >> 5;
  __shared__ ushort_t Ksm[2][64 * 64];   // double-buffered K [s][c]
  __shared__ ushort_t Vsm[2][64 * 64];   // double-buffered V [c][s]

  const ushort_t* kbase = kT + (size_t)bh * LL * CH;
  const ushort_t* vbase = vbuf + (size_t)bh * CH * LL;
  const int eb = w * 1024 + lane * 8;

  // stage tile 0 (K: contiguous 8KB; V: 128B row segments)
#pragma unroll
  for (int i = 0; i < 2; ++i) {
    int ee = eb + i * 512;
    g2l16(kbase + ee, &Ksm[0][w * 1024 + i * 512]);
    g2l16(vbase + (size_t)(ee >> 6) * LL + (ee & 63),
          &Vsm[0][w * 1024 + i * 512]);
  }
  // Q B-fragments: rows t = w*32+ln31, k-elems c = j*16 + hi*8 + 0..7
  const ushort_t* qtile = qT + ((size_t)bh * LL + t0g) * CH;
  short8 bq[4];
#pragma unroll
  for (int j = 0; j < 4; ++j)
    bq[j] = *(const short8*)&qtile[swz(w * 32 + ln31, j * 16 + hi * 8)];

  float m_s = 0.f, lsum = 0.f;
  f32x16 oacc[2];
  f32x16 zz = {0.f, 0.f, 0.f, 0.f, 0.f, 0.f, 0.f, 0.f,
               0.f, 0.f, 0.f, 0.f, 0.f, 0.f, 0.f, 0.f};
  oacc[0] = zz;
  oacc[1] = zz;
  __syncthreads();  // implicit vmcnt(0): buf0 staged

  int cur = 0;
  for (int it = 0; it < 16; ++it) {
    if (it < 15) {  // prefetch next tile; drained by end-of-iter barrier
      const ushort_t* kn = kbase + (size_t)(it + 1) * 64 * CH;
      const ushort_t* vn = vbase + (it + 1) * 64;
#pragma unroll
      for (int i = 0; i < 2; ++i) {
        int ee = eb + i * 512;
        g2l16(kn + ee, &Ksm[cur ^ 1][w * 1024 + i * 512]);
        g2l16(vn + (size_t)(ee >> 6) * LL + (ee & 63),
              &Vsm[cur ^ 1][w * 1024 + i * 512]);
      }
    }
    const ushort_t* Kc = Ksm[cur];
    const ushort_t* Vc = Vsm[cur];
    // S^T[s][t] = K Q^T (q pre-scaled by 0.125*log2e). Lane: t=ln31 (wave
    // strip), s = sq*32 + (r&3)+8*(r>>2)+4*hi.
    f32x16 sacc[2];
    sacc[0] = zz;
    sacc[1] = zz;
    __builtin_amdgcn_s_setprio(1);
#pragma unroll
    for (int sq = 0; sq < 2; ++sq)
#pragma unroll
      for (int j = 0; j < 4; ++j) {
        short8 ak = *(const short8*)&Kc[swz(sq * 32 + ln31, j * 16 + hi * 8)];
        sacc[sq] = __builtin_amdgcn_mfma_f32_32x32x16_bf16(ak, bq[j],
                                                           sacc[sq], 0, 0, 0);
      }
    __builtin_amdgcn_s_setprio(0);
    if (it == 0) {  // freeze softmax shift at tile-0 max (wave-uniform)
      float mx = sacc[0][0];
#pragma unroll
      for (int sq = 0; sq < 2; ++sq)
#pragma unroll
        for (int r = 0; r < 16; ++r) mx = fmaxf(mx, sacc[sq][r]);
#pragma unroll
      for (int off = 32; off > 0; off >>= 1) mx = fmaxf(mx, __shfl_xor(mx, off));
      m_s = mx;
    }
    // p = exp2(S' - m); pack to bf16; permlane32_swap exchanges s-halves so
    // each lane holds A-frag rows t=ln31, k-elems s = ks*16 + hi*8 + 0..7.
    short8 pf[4];
#pragma unroll
    for (int sq = 0; sq < 2; ++sq) {
      float p[16];
#pragma unroll
      for (int r = 0; r < 16; ++r) {
        p[r] = __builtin_amdgcn_exp2f(sacc[sq][r] - m_s);
        lsum += p[r];
      }
      unsigned d0[4], d1[4];
#pragma unroll
      for (int q = 0; q < 4; ++q) {
        d0[q] = pack_bf2(p[q * 4 + 0], p[q * 4 + 1]);
        d1[q] = pack_bf2(p[q * 4 + 2], p[q * 4 + 3]);
      }
#pragma unroll
      for (int m = 0; m < 2; ++m) {
        unsigned x0 = d0[m * 2], y0 = d0[m * 2 + 1];
        unsigned x1 = d1[m * 2], y1 = d1[m * 2 + 1];
        // dst lanes 32-63 <-> src lanes 0-31: x' = [X_lo|Y_lo], y' = [X_hi|Y_hi]
        asm volatile("v_permlane32_swap_b32 %0, %1" : "+v"(x0), "+v"(y0));
        asm volatile("v_permlane32_swap_b32 %0, %1" : "+v"(x1), "+v"(y1));
        union { uint4 u; short8 s; } fu;
        fu.u = make_uint4(x0, x1, y0, y1);
        pf[sq * 2 + m] = fu.s;
      }
    }
    // O[t][c] += P V^T
    __builtin_amdgcn_s_setprio(1);
#pragma unroll
    for (int cq = 0; cq < 2; ++cq)
#pragma unroll
      for (int ks = 0; ks < 4; ++ks) {
        short8 bv = *(const short8*)&Vc[swz(cq * 32 + ln31, ks * 16 + hi * 8)];
        oacc[cq] = __builtin_amdgcn_mfma_f32_32x32x16_bf16(pf[ks], bv,
                                                           oacc[cq], 0, 0, 0);
      }
    __builtin_amdgcn_s_setprio(0);
    __syncthreads();  // implicit vmcnt(0): next buf staged, cur consumed
    cur ^= 1;
  }
  // row sums: lane has half-s sum for t = ln31; merge with partner half
  lsum += __shfl_xor(lsum, 32);
#pragma unroll
  for (int r = 0; r < 16; ++r) {
    int tl = (r & 3) + 8 * (r >> 2) + 4 * hi;  // output t within wave strip
    float li = 1.f / __shfl(lsum, tl, 64);
    int lg = t0g + w * 32 + tl;
#pragma unroll
    for (int cq = 0; cq < 2; ++cq) {
      int cl = cq * 32 + ln31;
      // pre-swizzled abuf image (proj stages it linearly via DMA)
      int dcol = ((((cl >> 3) ^ (lg & 7)) << 3) | (cl & 7));
      abuf[((size_t)b * LL + lg) * CC + h * CH + dcol] =
          f2bf(oacc[cq][r] * li);
    }
  }
}

// ---------------- proj GEMM + bias + residual: 2-phase dbuf DMA ------------
__global__ __launch_bounds__(256) void proj_mfma_kernel(
    const ushort_t* __restrict__ wp, const ushort_t* __restrict__ abuf,
    const float* __restrict__ proj_b, const float* __restrict__ x,
    float* __restrict__ out) {
  const int b = blockIdx.z;
  const int m0 = blockIdx.y * 64;
  const int n0 = blockIdx.x * 128;
  const int tid = threadIdx.x;
  const int w = tid >> 6, lane = tid & 63;
  const int col = lane & 15, quad = lane >> 4;
  const int wm = (w >> 1) * 32, wn = (w & 1) * 64;
  __shared__ ushort_t Smem[2 * 12288];
  f32x4 acc[2][4];
  f32x4 z = {0.f, 0.f, 0.f, 0.f};
#pragma unroll
  for (int i = 0; i < 2; ++i)
#pragma unroll
    for (int j = 0; j < 4; ++j) acc[i][j] = z;

  const ushort_t* arow = wp + (size_t)m0 * CC;
  const ushort_t* brow = abuf + ((size_t)b * LL + n0) * CC;

  auto stage = [&](int bb, int k0) {
    ushort_t* As = Smem + bb * 12288;
    ushort_t* Bs = As + 4096;
#pragma unroll
    for (int j = 0; j < 2; ++j) {
      int e = (j * 4 + w) * 512 + lane * 8;
      g2l16(arow + (size_t)(e >> 6) * CC + k0 + (e & 63),
            As + (j * 4 + w) * 512);
    }
#pragma unroll
    for (int j = 0; j < 4; ++j) {
      int e = (j * 4 + w) * 512 + lane * 8;
      g2l16(brow + (size_t)(e >> 6) * CC + k0 + (e & 63),
            Bs + (j * 4 + w) * 512);
    }
  };

  stage(0, 0);
  __syncthreads();
  int cur = 0;
  for (int step = 0; step < 8; ++step) {
    if (step < 7) stage(cur ^ 1, (step + 1) * 64);
    const ushort_t* As = Smem + cur * 12288;
    const ushort_t* Bs = As + 4096;
#pragma unroll
    for (int kk = 0; kk < 2; ++kk) {
      short8 af[2], bf[4];
#pragma unroll
      for (int mi = 0; mi < 2; ++mi)
        af[mi] = *(const short8*)&As[swz(wm + mi * 16 + col, kk * 32 + quad * 8)];
#pragma unroll
      for (int ni = 0; ni < 4; ++ni)
        bf[ni] = *(const short8*)&Bs[swz(wn + ni * 16 + col, kk * 32 + quad * 8)];
#pragma unroll
      for (int mi = 0; mi < 2; ++mi)
#pragma unroll
        for (int ni = 0; ni < 4; ++ni)
          acc[mi][ni] = __builtin_amdgcn_mfma_f32_16x16x32_bf16(
              af[mi], bf[ni], acc[mi][ni], 0, 0, 0);
    }
    __syncthreads();
    cur ^= 1;
  }
#pragma unroll
  for (int mi = 0; mi < 2; ++mi)
#pragma unroll
    for (int r = 0; r < 4; ++r) {
      int o = m0 + wm + mi * 16 + quad * 4 + r;
      float bias = proj_b[o];
#pragma unroll
      for (int ni = 0; ni < 4; ++ni) {
        int l = n0 + wn + ni * 16 + col;
        size_t off = ((size_t)b * CC + o) * LL + l;
        out[off] = x[off] + bias + acc[mi][ni][r];
      }
    }
}

extern "C" void kernel_launch(void* const* d_in, const int* in_sizes, int n_in,
                              void* d_out, int out_size, void* d_ws,
                              size_t ws_size, hipStream_t stream) {
  const float* x = (const float*)d_in[0];
  const float* gn_w = (const float*)d_in[1];
  const float* gn_b = (const float*)d_in[2];
  const float* qkv_w = (const float*)d_in[3];
  const float* qkv_b = (const float*)d_in[4];
  const float* proj_w = (const float*)d_in[5];
  const float* proj_b = (const float*)d_in[6];
  float* out = (float*)d_out;

  char* ws = (char*)d_ws;
  float* s_bc = (float*)ws;
  float* t_bc = s_bc + BB * CC;
  ushort_t* wq = (ushort_t*)(t_bc + BB * CC);
  ushort_t* wp = wq + (size_t)3 * CC * CC;
  ushort_t* xnT = wp + (size_t)CC * CC;
  ushort_t* qT = xnT + (size_t)BB * LL * CC;
  ushort_t* kT = qT + (size_t)BB * NH * LL * CH;
  ushort_t* vb = kT + (size_t)BB * NH * LL * CH;
  ushort_t* abuf = vb + (size_t)BB * NH * LL * CH;

  pre_kernel<<<BB * GG + 1024, 256, 0, stream>>>(x, gn_w, gn_b, qkv_w, proj_w,
                                                 s_bc, t_bc, wq, wp);
  xnt_kernel<<<dim3(LL / 64, CC / 64, BB), 256, 0, stream>>>(x, s_bc, t_bc,
                                                             xnT);
  qkv_mfma_kernel<<<dim3(LL / 128, 1536 / 192, BB), 384, 0, stream>>>(
      wq, xnT, qkv_b, qT, kT, vb);
  attn_mfma_kernel<<<dim3(512), 256, 0, stream>>>(qT, kT, vb, abuf);
  proj_mfma_kernel<<<dim3(LL / 128, CC / 64, BB), 256, 0, stream>>>(
      wp, abuf, proj_b, x, out);
}